// Round 3
// baseline (843.587 us; speedup 1.0000x reference)
//
#include <hip/hip_runtime.h>
#include <cmath>

#define NPTS   1048576
#define NLVL   16
#define TMASK  ((1u << 19) - 1u)
#define P1     2654435761u
#define P2     805459861u

typedef float v2f __attribute__((ext_vector_type(2)));
typedef float v4f __attribute__((ext_vector_type(4)));

// One level per launch: the level's 4 MiB table is the only hot gather target,
// so it stays resident in every XCD's 4 MiB L2. Streaming data (x in, result
// out) is non-temporal. Result goes to a TRANSPOSED scratch [L][N][2] so each
// wave stores one dense 512 B block (no 8B-in-128B-stride partial lines).
__global__ __launch_bounds__(256) void hashgrid_lvl(
    const float* __restrict__ x,
    const float* __restrict__ tb,     // table + lvl*T*F
    float* __restrict__ wsl,          // ws + lvl*N*2  (or out+2*lvl fallback)
    float rf,
    int ostride)                      // 2 for ws layout, 32 for direct-out
{
    const int n = blockIdx.x * 256 + threadIdx.x;   // NPTS % 256 == 0

    const float px = __builtin_nontemporal_load(x + 3 * (size_t)n + 0);
    const float py = __builtin_nontemporal_load(x + 3 * (size_t)n + 1);
    const float pz = __builtin_nontemporal_load(x + 3 * (size_t)n + 2);

    // must match fp32 reference arithmetic exactly
    const float xs0 = px * rf, xs1 = py * rf, xs2 = pz * rf;
    const float f0 = floorf(xs0), f1 = floorf(xs1), f2 = floorf(xs2);
    const float w0 = xs0 - f0, w1 = xs1 - f1, w2 = xs2 - f2;

    const uint32_t i0 = (uint32_t)f0;
    const uint32_t i1 = (uint32_t)f1;
    const uint32_t i2 = (uint32_t)f2;

    const uint32_t A0 = i0,      A1 = i0 + 1u;
    const uint32_t B0 = i1 * P1, B1 = B0 + P1;
    const uint32_t C0 = i2 * P2, C1 = C0 + P2;

    // corner order = meshgrid(ij): dim0 slowest
    const uint32_t h000 = (A0 ^ B0 ^ C0) & TMASK;
    const uint32_t h001 = (A0 ^ B0 ^ C1) & TMASK;
    const uint32_t h010 = (A0 ^ B1 ^ C0) & TMASK;
    const uint32_t h011 = (A0 ^ B1 ^ C1) & TMASK;
    const uint32_t h100 = (A1 ^ B0 ^ C0) & TMASK;
    const uint32_t h101 = (A1 ^ B0 ^ C1) & TMASK;
    const uint32_t h110 = (A1 ^ B1 ^ C0) & TMASK;
    const uint32_t h111 = (A1 ^ B1 ^ C1) & TMASK;

    const float2 g000 = *(const float2*)(tb + 2 * (size_t)h000);
    const float2 g001 = *(const float2*)(tb + 2 * (size_t)h001);
    const float2 g010 = *(const float2*)(tb + 2 * (size_t)h010);
    const float2 g011 = *(const float2*)(tb + 2 * (size_t)h011);
    const float2 g100 = *(const float2*)(tb + 2 * (size_t)h100);
    const float2 g101 = *(const float2*)(tb + 2 * (size_t)h101);
    const float2 g110 = *(const float2*)(tb + 2 * (size_t)h110);
    const float2 g111 = *(const float2*)(tb + 2 * (size_t)h111);

    const float u0 = 1.0f - w0, u1 = 1.0f - w1, u2 = 1.0f - w2;
    const float wt000 = (u0 * u1) * u2;
    const float wt001 = (u0 * u1) * w2;
    const float wt010 = (u0 * w1) * u2;
    const float wt011 = (u0 * w1) * w2;
    const float wt100 = (w0 * u1) * u2;
    const float wt101 = (w0 * u1) * w2;
    const float wt110 = (w0 * w1) * u2;
    const float wt111 = (w0 * w1) * w2;

    float a0 = wt000 * g000.x;
    float a1 = wt000 * g000.y;
    a0 += wt001 * g001.x;  a1 += wt001 * g001.y;
    a0 += wt010 * g010.x;  a1 += wt010 * g010.y;
    a0 += wt011 * g011.x;  a1 += wt011 * g011.y;
    a0 += wt100 * g100.x;  a1 += wt100 * g100.y;
    a0 += wt101 * g101.x;  a1 += wt101 * g101.y;
    a0 += wt110 * g110.x;  a1 += wt110 * g110.y;
    a0 += wt111 * g111.x;  a1 += wt111 * g111.y;

    v2f r; r.x = a0; r.y = a1;
    __builtin_nontemporal_store(r, (v2f*)(wsl + (size_t)n * ostride));
}

// ws [L][N][2]  ->  out [N][L*2], all dense/coalesced both sides.
__global__ __launch_bounds__(256) void hashgrid_transpose(
    const float* __restrict__ ws,
    float* __restrict__ out)
{
    const int n = blockIdx.x * 256 + threadIdx.x;
    float acc[2 * NLVL];
#pragma unroll
    for (int l = 0; l < NLVL; ++l) {
        const v2f g = __builtin_nontemporal_load(
            (const v2f*)(ws + ((size_t)l << 21) + (size_t)n * 2));
        acc[2 * l + 0] = g.x;
        acc[2 * l + 1] = g.y;
    }
    v4f* op = (v4f*)(out + (size_t)n * 32);
#pragma unroll
    for (int k = 0; k < 8; ++k) {
        v4f v; v.x = acc[4*k]; v.y = acc[4*k+1]; v.z = acc[4*k+2]; v.w = acc[4*k+3];
        __builtin_nontemporal_store(v, op + k);
    }
}

extern "C" void kernel_launch(void* const* d_in, const int* in_sizes, int n_in,
                              void* d_out, int out_size, void* d_ws, size_t ws_size,
                              hipStream_t stream) {
    const float* x     = (const float*)d_in[0];
    const float* table = (const float*)d_in[1];
    float* out         = (float*)d_out;
    float* ws          = (float*)d_ws;

    // Reproduce Python's RESOLUTIONS bit-exactly using the same libm
    // (volatile fn pointers stop clang from folding/strength-reducing pow).
    double (*volatile p_log)(double)          = log;
    double (*volatile p_exp)(double)          = exp;
    double (*volatile p_pow)(double, double)  = pow;
    double (*volatile p_floor)(double)        = floor;

    const double b = p_exp((p_log(2048.0) - p_log(16.0)) / 15.0);

    const bool use_ws = ws_size >= (size_t)NLVL * NPTS * 2 * sizeof(float);

    for (int l = 0; l < NLVL; ++l) {
        const int res = (int)p_floor(16.0 * p_pow(b, (double)l));
        if (use_ws) {
            hashgrid_lvl<<<NPTS / 256, 256, 0, stream>>>(
                x, table + ((size_t)l << 20), ws + ((size_t)l << 21),
                (float)res, 2);
        } else {
            hashgrid_lvl<<<NPTS / 256, 256, 0, stream>>>(
                x, table + ((size_t)l << 20), out + 2 * l,
                (float)res, 32);
        }
    }
    if (use_ws) {
        hashgrid_transpose<<<NPTS / 256, 256, 0, stream>>>(ws, out);
    }
}

// Round 4
// 571.580 us; speedup vs baseline: 1.4759x; 1.4759x over previous
//
#include <hip/hip_runtime.h>
#include <cmath>

#define NPTS   1048576
#define NLVL   16
#define TMASK  ((1u << 19) - 1u)
#define P1     2654435761u
#define P2     805459861u

typedef float v2f __attribute__((ext_vector_type(2)));
typedef float v4f __attribute__((ext_vector_type(4)));

// One level per launch: the level's 4 MiB table is the only hot gather target,
// so it stays resident in every XCD's 4 MiB L2. Streaming data (x in, result
// out) is non-temporal. Result goes to a TRANSPOSED scratch [L][N][2] so each
// wave stores one dense 512 B block (no 8B-in-128B-stride partial lines).
__global__ __launch_bounds__(256) void hashgrid_lvl(
    const float* __restrict__ x,
    const float* __restrict__ tb,     // table + lvl*T*F
    float* __restrict__ wsl,          // ws + lvl*N*2  (or out+2*lvl fallback)
    float rf,
    int ostride)                      // 2 for ws layout, 32 for direct-out
{
    const int n = blockIdx.x * 256 + threadIdx.x;   // NPTS % 256 == 0

    const float px = __builtin_nontemporal_load(x + 3 * (size_t)n + 0);
    const float py = __builtin_nontemporal_load(x + 3 * (size_t)n + 1);
    const float pz = __builtin_nontemporal_load(x + 3 * (size_t)n + 2);

    // must match fp32 reference arithmetic exactly
    const float xs0 = px * rf, xs1 = py * rf, xs2 = pz * rf;
    const float f0 = floorf(xs0), f1 = floorf(xs1), f2 = floorf(xs2);
    const float w0 = xs0 - f0, w1 = xs1 - f1, w2 = xs2 - f2;

    const uint32_t i0 = (uint32_t)f0;
    const uint32_t i1 = (uint32_t)f1;
    const uint32_t i2 = (uint32_t)f2;

    const uint32_t A0 = i0,      A1 = i0 + 1u;
    const uint32_t B0 = i1 * P1, B1 = B0 + P1;
    const uint32_t C0 = i2 * P2, C1 = C0 + P2;

    // corner order = meshgrid(ij): dim0 slowest
    const uint32_t h000 = (A0 ^ B0 ^ C0) & TMASK;
    const uint32_t h001 = (A0 ^ B0 ^ C1) & TMASK;
    const uint32_t h010 = (A0 ^ B1 ^ C0) & TMASK;
    const uint32_t h011 = (A0 ^ B1 ^ C1) & TMASK;
    const uint32_t h100 = (A1 ^ B0 ^ C0) & TMASK;
    const uint32_t h101 = (A1 ^ B0 ^ C1) & TMASK;
    const uint32_t h110 = (A1 ^ B1 ^ C0) & TMASK;
    const uint32_t h111 = (A1 ^ B1 ^ C1) & TMASK;

    const float2 g000 = *(const float2*)(tb + 2 * (size_t)h000);
    const float2 g001 = *(const float2*)(tb + 2 * (size_t)h001);
    const float2 g010 = *(const float2*)(tb + 2 * (size_t)h010);
    const float2 g011 = *(const float2*)(tb + 2 * (size_t)h011);
    const float2 g100 = *(const float2*)(tb + 2 * (size_t)h100);
    const float2 g101 = *(const float2*)(tb + 2 * (size_t)h101);
    const float2 g110 = *(const float2*)(tb + 2 * (size_t)h110);
    const float2 g111 = *(const float2*)(tb + 2 * (size_t)h111);

    const float u0 = 1.0f - w0, u1 = 1.0f - w1, u2 = 1.0f - w2;
    const float wt000 = (u0 * u1) * u2;
    const float wt001 = (u0 * u1) * w2;
    const float wt010 = (u0 * w1) * u2;
    const float wt011 = (u0 * w1) * w2;
    const float wt100 = (w0 * u1) * u2;
    const float wt101 = (w0 * u1) * w2;
    const float wt110 = (w0 * w1) * u2;
    const float wt111 = (w0 * w1) * w2;

    float a0 = wt000 * g000.x;
    float a1 = wt000 * g000.y;
    a0 += wt001 * g001.x;  a1 += wt001 * g001.y;
    a0 += wt010 * g010.x;  a1 += wt010 * g010.y;
    a0 += wt011 * g011.x;  a1 += wt011 * g011.y;
    a0 += wt100 * g100.x;  a1 += wt100 * g100.y;
    a0 += wt101 * g101.x;  a1 += wt101 * g101.y;
    a0 += wt110 * g110.x;  a1 += wt110 * g110.y;
    a0 += wt111 * g111.x;  a1 += wt111 * g111.y;

    if (ostride == 2) {
        // dense [L][N][2] scratch: full-line wave stores, NT keeps L2 for table
        v2f r; r.x = a0; r.y = a1;
        __builtin_nontemporal_store(r, (v2f*)(wsl + (size_t)n * 2));
    } else {
        // fallback direct-out: partial-line — must be CACHED so L2 merges
        wsl[(size_t)n * 32 + 0] = a0;
        wsl[(size_t)n * 32 + 1] = a1;
    }
}

// ws [L][N][2]  ->  out [N][L*2]. Loads NT (ws never reused, L3-resident);
// stores REGULAR so L2 merges each thread's 8x16B into one 128B line.
__global__ __launch_bounds__(256) void hashgrid_transpose(
    const float* __restrict__ ws,
    float* __restrict__ out)
{
    const int n = blockIdx.x * 256 + threadIdx.x;
    float acc[2 * NLVL];
#pragma unroll
    for (int l = 0; l < NLVL; ++l) {
        const v2f g = __builtin_nontemporal_load(
            (const v2f*)(ws + ((size_t)l << 21) + (size_t)n * 2));
        acc[2 * l + 0] = g.x;
        acc[2 * l + 1] = g.y;
    }
    v4f* op = (v4f*)(out + (size_t)n * 32);
#pragma unroll
    for (int k = 0; k < 8; ++k) {
        v4f v; v.x = acc[4*k]; v.y = acc[4*k+1]; v.z = acc[4*k+2]; v.w = acc[4*k+3];
        op[k] = v;   // cached store -> full-line writeback
    }
}

extern "C" void kernel_launch(void* const* d_in, const int* in_sizes, int n_in,
                              void* d_out, int out_size, void* d_ws, size_t ws_size,
                              hipStream_t stream) {
    const float* x     = (const float*)d_in[0];
    const float* table = (const float*)d_in[1];
    float* out         = (float*)d_out;
    float* ws          = (float*)d_ws;

    // Reproduce Python's RESOLUTIONS bit-exactly using the same libm
    // (volatile fn pointers stop clang from folding/strength-reducing pow).
    double (*volatile p_log)(double)          = log;
    double (*volatile p_exp)(double)          = exp;
    double (*volatile p_pow)(double, double)  = pow;
    double (*volatile p_floor)(double)        = floor;

    const double b = p_exp((p_log(2048.0) - p_log(16.0)) / 15.0);

    const bool use_ws = ws_size >= (size_t)NLVL * NPTS * 2 * sizeof(float);

    for (int l = 0; l < NLVL; ++l) {
        const int res = (int)p_floor(16.0 * p_pow(b, (double)l));
        if (use_ws) {
            hashgrid_lvl<<<NPTS / 256, 256, 0, stream>>>(
                x, table + ((size_t)l << 20), ws + ((size_t)l << 21),
                (float)res, 2);
        } else {
            hashgrid_lvl<<<NPTS / 256, 256, 0, stream>>>(
                x, table + ((size_t)l << 20), out + 2 * l,
                (float)res, 32);
        }
    }
    if (use_ws) {
        hashgrid_transpose<<<NPTS / 256, 256, 0, stream>>>(ws, out);
    }
}